// Round 8
// baseline (761.006 us; speedup 1.0000x reference)
//
#include <hip/hip_runtime.h>

// GRU: B=256, T=1000, I=64, H=128.
// Round-8 = round-7 with the DPP ctrl as a template constant (compile fix).
// Defeat AGPR demotion BY CONSTRUCTION: 1024 threads/block (4 waves/SIMD,
// hard 128-reg/thread cap), tid = j*8+ks: j in [0,128) hidden unit,
// ks in [0,8) k-slice. Per-thread weights: 3 gate-rows x (16 W_hh + 8 W_ih)
// = 72 floats + ~40 working < 128 -> nothing left to demote.
// 8-lane reduce: 3 DPP levels — quad xor1 (0xB1), quad xor2 (0x4E),
// row_half_mirror (0x141, lane i<->i^7) — pure VALU, no LDS permute.

#define Bc 256
#define Tc 1000
#define Ic 64
#define Hc 128

#define HSKEW(k) ((k) + (((k) >> 5) << 2))
#define HBUF_W (Hc + 16)

__device__ __forceinline__ float fast_sigmoid(float x) {
    return __builtin_amdgcn_rcpf(1.0f + __expf(-x));
}
__device__ __forceinline__ float fast_tanh(float x) {
    return 1.0f - 2.0f * __builtin_amdgcn_rcpf(__expf(2.0f * x) + 1.0f);
}
template <int CTRL>
__device__ __forceinline__ float dpp_add(float x) {
    int y = __builtin_amdgcn_update_dpp(0, __float_as_int(x), CTRL, 0xF, 0xF, true);
    return x + __int_as_float(y);
}
// sum over the 8 lanes of an aligned 8-lane group (j-group)
__device__ __forceinline__ float oct_reduce(float x) {
    x = dpp_add<0xB1>(x);    // quad_perm [1,0,3,2]  : + lane^1
    x = dpp_add<0x4E>(x);    // quad_perm [2,3,0,1]  : + lane^2
    x = dpp_add<0x141>(x);   // row_half_mirror      : + lane^7 (other quad)
    return x;
}

__global__ __launch_bounds__(1024) void gru_scan_kernel(
    const float* __restrict__ input,   // [B][T][I]
    const float* __restrict__ W_ih,    // [3H][I]
    const float* __restrict__ W_hh,    // [3H][H]
    const float* __restrict__ b_ih,    // [3H]
    const float* __restrict__ b_hh,    // [3H]
    float* __restrict__ out)           // states [B][T][H] then hT [B][H]
{
    const int b   = blockIdx.x;
    const int tid = threadIdx.x;
    const int j   = tid >> 3;
    const int ks  = tid & 7;

    __shared__ float hbuf[2][HBUF_W];
    __shared__ float ibuf[2][Ic];

    // ---- persistent weights: 72 floats/thread ----
    float wr[16], wz[16], wn[16];   // W_hh rows {j, H+j, 2H+j}, cols [16ks,16ks+16)
    {
        const float* pr = W_hh + (size_t)j * Hc + ks * 16;
        const float* pz = W_hh + (size_t)(Hc + j) * Hc + ks * 16;
        const float* pn = W_hh + (size_t)(2 * Hc + j) * Hc + ks * 16;
#pragma unroll
        for (int q = 0; q < 4; ++q) {
            *reinterpret_cast<float4*>(&wr[q * 4]) = reinterpret_cast<const float4*>(pr)[q];
            *reinterpret_cast<float4*>(&wz[q * 4]) = reinterpret_cast<const float4*>(pz)[q];
            *reinterpret_cast<float4*>(&wn[q * 4]) = reinterpret_cast<const float4*>(pn)[q];
        }
    }
    float ur[8], uz[8], un[8];      // W_ih rows, cols [8ks,8ks+8)
    {
        const float* pr = W_ih + (size_t)j * Ic + ks * 8;
        const float* pz = W_ih + (size_t)(Hc + j) * Ic + ks * 8;
        const float* pn = W_ih + (size_t)(2 * Hc + j) * Ic + ks * 8;
#pragma unroll
        for (int q = 0; q < 2; ++q) {
            *reinterpret_cast<float4*>(&ur[q * 4]) = reinterpret_cast<const float4*>(pr)[q];
            *reinterpret_cast<float4*>(&uz[q * 4]) = reinterpret_cast<const float4*>(pz)[q];
            *reinterpret_cast<float4*>(&un[q * 4]) = reinterpret_cast<const float4*>(pn)[q];
        }
    }
    // biases pre-scaled by 1/8 (8-lane reduce restores 1x)
    const float br8  = 0.125f * (b_ih[j] + b_hh[j]);
    const float bz8  = 0.125f * (b_ih[Hc + j] + b_hh[Hc + j]);
    const float bnx8 = 0.125f * b_ih[2 * Hc + j];
    const float bnh8 = 0.125f * b_hh[2 * Hc + j];

    const float* inp_b    = input + (size_t)b * Tc * Ic;
    float*       states_b = out + (size_t)b * Tc * Hc;
    float*       hT_out   = out + (size_t)Bc * Tc * Hc + (size_t)b * Hc;

    // ---- prologue: h0 = 0, stage input rows 0 and 1 ----
    float in_t1 = 0.0f;
    if (tid < Ic) {
        ibuf[0][tid] = inp_b[tid];
        in_t1        = inp_b[Ic + tid];  // row 1
    }
    if (tid < HBUF_W) hbuf[0][tid] = 0.0f;
    __syncthreads();

    for (int t = 0; t < Tc; ++t) {
        const int rb = t & 1;
        const int wb = rb ^ 1;

        // prefetch input row t+2
        float in_t2 = 0.0f;
        if (tid < Ic) {
            const int tn = (t + 2 < Tc) ? (t + 2) : (Tc - 1);
            in_t2 = inp_b[(size_t)tn * Ic + tid];
        }

        const float h_old = hbuf[rb][HSKEW(j)];

        float ar = br8;    // r gate (x+h combined)
        float az = bz8;    // z gate (x+h combined)
        float ah = bnh8;   // n gate, hidden part
        float ax = bnx8;   // n gate, input part

        // hidden dot: k in [16ks, 16ks+16)  (skew-contiguous, bank-disjoint)
        const float* hb = &hbuf[rb][HSKEW(ks * 16)];
#pragma unroll
        for (int q = 0; q < 4; ++q) {
            const float4 hv = *reinterpret_cast<const float4*>(hb + q * 4);
            ar = fmaf(hv.x, wr[4 * q + 0], ar);
            az = fmaf(hv.x, wz[4 * q + 0], az);
            ah = fmaf(hv.x, wn[4 * q + 0], ah);
            ar = fmaf(hv.y, wr[4 * q + 1], ar);
            az = fmaf(hv.y, wz[4 * q + 1], az);
            ah = fmaf(hv.y, wn[4 * q + 1], ah);
            ar = fmaf(hv.z, wr[4 * q + 2], ar);
            az = fmaf(hv.z, wz[4 * q + 2], az);
            ah = fmaf(hv.z, wn[4 * q + 2], ah);
            ar = fmaf(hv.w, wr[4 * q + 3], ar);
            az = fmaf(hv.w, wz[4 * q + 3], az);
            ah = fmaf(hv.w, wn[4 * q + 3], ah);
        }
        // input dot: k' in [8ks, 8ks+8)
        const float* ib = &ibuf[rb][ks * 8];
#pragma unroll
        for (int q = 0; q < 2; ++q) {
            const float4 iv = *reinterpret_cast<const float4*>(ib + q * 4);
            ar = fmaf(iv.x, ur[4 * q + 0], ar);
            az = fmaf(iv.x, uz[4 * q + 0], az);
            ax = fmaf(iv.x, un[4 * q + 0], ax);
            ar = fmaf(iv.y, ur[4 * q + 1], ar);
            az = fmaf(iv.y, uz[4 * q + 1], az);
            ax = fmaf(iv.y, un[4 * q + 1], ax);
            ar = fmaf(iv.z, ur[4 * q + 2], ar);
            az = fmaf(iv.z, uz[4 * q + 2], az);
            ax = fmaf(iv.z, un[4 * q + 2], ax);
            ar = fmaf(iv.w, ur[4 * q + 3], ar);
            az = fmaf(iv.w, uz[4 * q + 3], az);
            ax = fmaf(iv.w, un[4 * q + 3], ax);
        }

        // 8-lane reduce: pure DPP (valid in all 8 lanes of the j-group)
        ar = oct_reduce(ar);
        az = oct_reduce(az);
        ah = oct_reduce(ah);
        ax = oct_reduce(ax);

        // gates (replicated across the 8-lane group)
        const float r    = fast_sigmoid(ar);
        const float z    = fast_sigmoid(az);
        const float n    = fast_tanh(ax + r * ah);
        const float hnew = n + z * (h_old - n);

        // spread epilogue stores across group lanes
        if (ks == 0) hbuf[wb][HSKEW(j)] = hnew;
        else if (ks == 1) states_b[(size_t)t * Hc + j] = hnew;
        else if (ks == 2) { if (t == Tc - 1) hT_out[j] = hnew; }
        if (tid < Ic) {
            ibuf[wb][tid] = in_t1;
            in_t1 = in_t2;
        }
        __syncthreads();
    }
}

extern "C" void kernel_launch(void* const* d_in, const int* in_sizes, int n_in,
                              void* d_out, int out_size, void* d_ws, size_t ws_size,
                              hipStream_t stream) {
    const float* input = (const float*)d_in[0];
    const float* W_ih  = (const float*)d_in[1];
    const float* W_hh  = (const float*)d_in[2];
    const float* b_ih  = (const float*)d_in[3];
    const float* b_hh  = (const float*)d_in[4];
    float* out = (float*)d_out;
    (void)in_sizes; (void)n_in; (void)d_ws; (void)ws_size; (void)out_size;

    gru_scan_kernel<<<Bc, 1024, 0, stream>>>(input, W_ih, W_hh, b_ih, b_hh, out);
}

// Round 9
// 695.612 us; speedup vs baseline: 1.0940x; 1.0940x over previous
//
#include <hip/hip_runtime.h>

// GRU: B=256, T=1000, I=64, H=128.
// Round-9: fp16-packed weights/activations + v_dot2_f32_f16 (fp32 accum).
// Evidence r1..r8: kernel is VALU-ISSUE-bound (r8: VALUBusy 99.4%); allocator
// caps arch VGPRs at ~0.4x budget at every config, demoting fp32 weight
// arrays to AGPRs (move per use). dot2 halves BOTH the FMA issue count
// (144->72/thread) and the weight register footprint (144->72 packed regs),
// fitting the observed ~104-arch split at 512 threads.
// Recurrent carry h stays fp32 (hbuf32); fp16 only inside the dot products.
// Structure = r1/r5 known-good: 1 batch row/block, 512 threads, tid=j*4+ks,
// 1 barrier/step, DPP quad reduce, biases folded (x0.25) into acc init.

#define Bc 256
#define Tc 1000
#define Ic 64
#define Hc 128

typedef _Float16 f16x2 __attribute__((ext_vector_type(2)));

#if __has_builtin(__builtin_amdgcn_fdot2)
#define FDOT2(a, b, c) __builtin_amdgcn_fdot2((a), (b), (c), false)
#else
#define FDOT2(a, b, c) fmaf((float)(a).x, (float)(b).x, fmaf((float)(a).y, (float)(b).y, (c)))
#endif

__device__ __forceinline__ float fast_sigmoid(float x) {
    return __builtin_amdgcn_rcpf(1.0f + __expf(-x));
}
__device__ __forceinline__ float fast_tanh(float x) {
    return 1.0f - 2.0f * __builtin_amdgcn_rcpf(__expf(2.0f * x) + 1.0f);
}
template <int CTRL>
__device__ __forceinline__ float dpp_add(float x) {
    int y = __builtin_amdgcn_update_dpp(0, __float_as_int(x), CTRL, 0xF, 0xF, true);
    return x + __int_as_float(y);
}
// sum over the 4 lanes of an aligned quad
__device__ __forceinline__ float quad_reduce(float x) {
    x = dpp_add<0xB1>(x);   // + lane^1
    x = dpp_add<0x4E>(x);   // + lane^2
    return x;
}
__device__ __forceinline__ f16x2 pack2(float a, float b) {
    f16x2 r; r.x = (_Float16)a; r.y = (_Float16)b; return r;
}

__global__ __launch_bounds__(512, 1) void gru_scan_kernel(
    const float* __restrict__ input,   // [B][T][I]
    const float* __restrict__ W_ih,    // [3H][I]
    const float* __restrict__ W_hh,    // [3H][H]
    const float* __restrict__ b_ih,    // [3H]
    const float* __restrict__ b_hh,    // [3H]
    float* __restrict__ out)           // states [B][T][H] then hT [B][H]
{
    const int b   = blockIdx.x;
    const int tid = threadIdx.x;
    const int j   = tid >> 2;
    const int ks  = tid & 3;

    __shared__ __align__(16) _Float16 hbuf16[2][Hc];  // h as fp16 (dot operand)
    __shared__ float                  hbuf32[2][Hc];  // h carry, full fp32
    __shared__ __align__(16) _Float16 ibuf16[2][Ic];  // x row as fp16

    // ---- persistent weights, fp16-packed: 72 h2 regs/thread ----
    f16x2 wr[16], wz[16], wn[16];   // W_hh rows {j,H+j,2H+j}, cols [32ks,32ks+32)
    {
        const float4* pr = reinterpret_cast<const float4*>(W_hh + (size_t)j * Hc + ks * 32);
        const float4* pz = reinterpret_cast<const float4*>(W_hh + (size_t)(Hc + j) * Hc + ks * 32);
        const float4* pn = reinterpret_cast<const float4*>(W_hh + (size_t)(2 * Hc + j) * Hc + ks * 32);
#pragma unroll
        for (int q = 0; q < 8; ++q) {
            const float4 a = pr[q]; wr[2 * q] = pack2(a.x, a.y); wr[2 * q + 1] = pack2(a.z, a.w);
            const float4 c = pz[q]; wz[2 * q] = pack2(c.x, c.y); wz[2 * q + 1] = pack2(c.z, c.w);
            const float4 d = pn[q]; wn[2 * q] = pack2(d.x, d.y); wn[2 * q + 1] = pack2(d.z, d.w);
        }
    }
    f16x2 ur[8], uz[8], un[8];      // W_ih rows, cols [16ks,16ks+16)
    {
        const float4* pr = reinterpret_cast<const float4*>(W_ih + (size_t)j * Ic + ks * 16);
        const float4* pz = reinterpret_cast<const float4*>(W_ih + (size_t)(Hc + j) * Ic + ks * 16);
        const float4* pn = reinterpret_cast<const float4*>(W_ih + (size_t)(2 * Hc + j) * Ic + ks * 16);
#pragma unroll
        for (int q = 0; q < 4; ++q) {
            const float4 a = pr[q]; ur[2 * q] = pack2(a.x, a.y); ur[2 * q + 1] = pack2(a.z, a.w);
            const float4 c = pz[q]; uz[2 * q] = pack2(c.x, c.y); uz[2 * q + 1] = pack2(c.z, c.w);
            const float4 d = pn[q]; un[2 * q] = pack2(d.x, d.y); un[2 * q + 1] = pack2(d.z, d.w);
        }
    }
    // biases pre-scaled by 1/4 (quad reduce restores 1x)
    const float br4  = 0.25f * (b_ih[j] + b_hh[j]);
    const float bz4  = 0.25f * (b_ih[Hc + j] + b_hh[Hc + j]);
    const float bnx4 = 0.25f * b_ih[2 * Hc + j];
    const float bnh4 = 0.25f * b_hh[2 * Hc + j];

    const float* inp_b    = input + (size_t)b * Tc * Ic;
    float*       states_b = out + (size_t)b * Tc * Hc;
    float*       hT_out   = out + (size_t)Bc * Tc * Hc + (size_t)b * Hc;

    // ---- prologue: h0 = 0, stage input rows 0 and 1 ----
    float in_t1 = 0.0f;
    if (tid < Ic) {
        ibuf16[0][tid] = (_Float16)inp_b[tid];
        in_t1          = inp_b[Ic + tid];  // row 1
    }
    if (tid < Hc) { hbuf16[0][tid] = (_Float16)0.0f; hbuf32[0][tid] = 0.0f; }
    __syncthreads();

    for (int t = 0; t < Tc; ++t) {
        const int rb = t & 1;
        const int wb = rb ^ 1;

        // prefetch input row t+2
        float in_t2 = 0.0f;
        if (tid < Ic) {
            const int tn = (t + 2 < Tc) ? (t + 2) : (Tc - 1);
            in_t2 = inp_b[(size_t)tn * Ic + tid];
        }

        const float h_old = hbuf32[rb][j];

        float ar0 = br4,  ar1 = 0.f;
        float az0 = bz4,  az1 = 0.f;
        float ah0 = bnh4, ah1 = 0.f;
        float ax0 = bnx4, ax1 = 0.f;

        // hidden dot: 32 h values = 16 fp16 pairs, 4x ds_read_b128
        const uint4* hb = reinterpret_cast<const uint4*>(&hbuf16[rb][ks * 32]);
#pragma unroll
        for (int q = 0; q < 4; ++q) {
            const uint4 hv = hb[q];
            const f16x2 p0 = __builtin_bit_cast(f16x2, hv.x);
            const f16x2 p1 = __builtin_bit_cast(f16x2, hv.y);
            const f16x2 p2 = __builtin_bit_cast(f16x2, hv.z);
            const f16x2 p3 = __builtin_bit_cast(f16x2, hv.w);
            ar0 = FDOT2(p0, wr[4 * q + 0], ar0);
            az0 = FDOT2(p0, wz[4 * q + 0], az0);
            ah0 = FDOT2(p0, wn[4 * q + 0], ah0);
            ar1 = FDOT2(p1, wr[4 * q + 1], ar1);
            az1 = FDOT2(p1, wz[4 * q + 1], az1);
            ah1 = FDOT2(p1, wn[4 * q + 1], ah1);
            ar0 = FDOT2(p2, wr[4 * q + 2], ar0);
            az0 = FDOT2(p2, wz[4 * q + 2], az0);
            ah0 = FDOT2(p2, wn[4 * q + 2], ah0);
            ar1 = FDOT2(p3, wr[4 * q + 3], ar1);
            az1 = FDOT2(p3, wz[4 * q + 3], az1);
            ah1 = FDOT2(p3, wn[4 * q + 3], ah1);
        }
        // input dot: 16 x values = 8 pairs, 2x ds_read_b128
        const uint4* xb = reinterpret_cast<const uint4*>(&ibuf16[rb][ks * 16]);
#pragma unroll
        for (int q = 0; q < 2; ++q) {
            const uint4 xv = xb[q];
            const f16x2 p0 = __builtin_bit_cast(f16x2, xv.x);
            const f16x2 p1 = __builtin_bit_cast(f16x2, xv.y);
            const f16x2 p2 = __builtin_bit_cast(f16x2, xv.z);
            const f16x2 p3 = __builtin_bit_cast(f16x2, xv.w);
            ar0 = FDOT2(p0, ur[4 * q + 0], ar0);
            az0 = FDOT2(p0, uz[4 * q + 0], az0);
            ax0 = FDOT2(p0, un[4 * q + 0], ax0);
            ar1 = FDOT2(p1, ur[4 * q + 1], ar1);
            az1 = FDOT2(p1, uz[4 * q + 1], az1);
            ax1 = FDOT2(p1, un[4 * q + 1], ax1);
            ar0 = FDOT2(p2, ur[4 * q + 2], ar0);
            az0 = FDOT2(p2, uz[4 * q + 2], az0);
            ax0 = FDOT2(p2, un[4 * q + 2], ax0);
            ar1 = FDOT2(p3, ur[4 * q + 3], ar1);
            az1 = FDOT2(p3, uz[4 * q + 3], az1);
            ax1 = FDOT2(p3, un[4 * q + 3], ax1);
        }

        // quad reduce: 2 DPP levels, pure VALU
        const float ar = quad_reduce(ar0 + ar1);
        const float az = quad_reduce(az0 + az1);
        const float ah = quad_reduce(ah0 + ah1);
        const float ax = quad_reduce(ax0 + ax1);

        // gates (replicated across the quad)
        const float r    = fast_sigmoid(ar);
        const float z    = fast_sigmoid(az);
        const float n    = fast_tanh(ax + r * ah);
        const float hnew = n + z * (h_old - n);

        // spread epilogue stores across quad lanes
        if (ks == 0) hbuf32[wb][j] = hnew;
        else if (ks == 3) hbuf16[wb][j] = (_Float16)hnew;
        else if (ks == 1) states_b[(size_t)t * Hc + j] = hnew;
        else { if (t == Tc - 1) hT_out[j] = hnew; }
        if (tid < Ic) {
            ibuf16[wb][tid] = (_Float16)in_t1;
            in_t1 = in_t2;
        }
        __syncthreads();
    }
}

extern "C" void kernel_launch(void* const* d_in, const int* in_sizes, int n_in,
                              void* d_out, int out_size, void* d_ws, size_t ws_size,
                              hipStream_t stream) {
    const float* input = (const float*)d_in[0];
    const float* W_ih  = (const float*)d_in[1];
    const float* W_hh  = (const float*)d_in[2];
    const float* b_ih  = (const float*)d_in[3];
    const float* b_hh  = (const float*)d_in[4];
    float* out = (float*)d_out;
    (void)in_sizes; (void)n_in; (void)d_ws; (void)ws_size; (void)out_size;

    gru_scan_kernel<<<Bc, 512, 0, stream>>>(input, W_ih, W_hh, b_ih, b_hh, out);
}